// Round 9
// baseline (1024.182 us; speedup 1.0000x reference)
//
#include <hip/hip_runtime.h>
#include <hip/hip_bf16.h>

#define KNN_K 20
typedef _Float16 f16;
typedef _Float16 half8 __attribute__((ext_vector_type(8)));
typedef float f32x4 __attribute__((ext_vector_type(4)));

__device__ __forceinline__ float lrelu(float x){ return x >= 0.f ? x : 0.2f*x; }
__device__ __forceinline__ f16 us2h(unsigned short u){ union{unsigned short u; f16 h;} x; x.u=u; return x.h; }
__device__ __forceinline__ unsigned short h2us(f16 h){ union{unsigned short u; f16 h;} x; x.h=h; return x.u; }

// u32 key: [31:16] order-mapped f16 distance (desc), [15:0] ~m (idx asc). Unique, always > 0.
__device__ __forceinline__ unsigned pack_key16(f16 v, int m){
  unsigned u = h2us(v);
  unsigned s = (u & 0x8000u) ? ((~u) & 0xFFFFu) : (u | 0x8000u);
  return (s << 16) | ((~(unsigned)m) & 0xFFFFu);
}

// sorted-desc insert via min/max carry chain: 2 VALU/slot, branchless body.
__device__ __forceinline__ void insert32(unsigned* tk, unsigned key){
  if (key > tk[KNN_K-1]){
    unsigned c = key;
    #pragma unroll
    for (int j=0;j<KNN_K;++j){
      unsigned hi = max(tk[j], c);
      unsigned lo = min(tk[j], c);
      tk[j] = hi;
      c = lo;
    }
  }
}

__device__ __forceinline__ void merge_sorted(unsigned* tk, const unsigned* src){
  #pragma unroll
  for (int j=0;j<KNN_K;++j){
    unsigned key = src[j];
    if (key <= tk[KNN_K-1]) break;
    insert32(tk, key);
  }
}

// ---------------- build x0: CN f32 + padded f16 NC + xx ----------------
__global__ __launch_bounds__(256) void build_x0(
    const float* __restrict__ pos, const int* __restrict__ nt,
    float* __restrict__ x0CN, unsigned short* __restrict__ xh0,
    unsigned short* __restrict__ xx0, int N)
{
  int n = blockIdx.x*256 + threadIdx.x;
  if (n >= N) return;
  float v[12];
  v[0]=pos[n*3+0]; v[1]=pos[n*3+1]; v[2]=pos[n*3+2];
  int t = nt[n];
  #pragma unroll
  for (int c=0;c<9;++c) v[3+c] = (t==c) ? 1.f : 0.f;
  float xa = 0.f;
  #pragma unroll
  for (int c=0;c<12;++c){
    x0CN[(size_t)c*N+n] = v[c];
    f16 h = (f16)v[c];
    float hf = (float)h;
    xh0[(size_t)n*32+c] = h2us(h);
    f16 pe = (f16)(hf*hf);       // elementwise xh*xh rounds to f16
    xa += (float)pe;             // f32 accumulation (jax upcast semantics)
  }
  #pragma unroll
  for (int c=12;c<32;++c) xh0[(size_t)n*32+c] = 0;
  xx0[n] = h2us((f16)xa);
}

// ---------------- weight transpose: dst[c*O+o] = src[o*stride+coff+c] ----------------
__global__ __launch_bounds__(256) void transpose_w(
    const float* __restrict__ src, float* __restrict__ dst, int O, int C, int stride, int coff)
{
  int i = blockIdx.x*256 + threadIdx.x;
  if (i >= O*C) return;
  int o = i / C, c = i % C;
  dst[(size_t)c*O + o] = src[(size_t)o*stride + coff + c];
}

// ---------------- fused MFMA kNN: grid (N/16, 2 m-halves), 512 thr ----------------
// LDS = 40960 B exactly -> 4 blocks/CU (was 46080 -> 3/CU, 33% tail idle).
template<int C>
__global__ __launch_bounds__(512) void knn_mfma(
    const unsigned short* __restrict__ xh,  // [N][C] f16 bits
    const unsigned short* __restrict__ xx,  // [N]   f16 bits
    unsigned* __restrict__ pl,              // [2][N][20] partial sorted keys
    int N)
{
  __shared__ unsigned lists[32][16][KNN_K];  // 40960 B exactly
  int tid = threadIdx.x;
  int w = tid >> 6, lane = tid & 63;
  int g = lane >> 4, c = lane & 15;
  int n0 = blockIdx.x * 16;
  int ms = blockIdx.y;
  int htiles = (N >> 7);            // tiles of 64 in this half

  half8 bfrag[C/32];
  #pragma unroll
  for (int kc=0; kc<C/32; ++kc)
    bfrag[kc] = *reinterpret_cast<const half8*>(xh + (size_t)(n0 + c)*C + kc*32 + g*8);
  f16 qxx = us2h(xx[n0 + c]);

  unsigned tk[KNN_K];
  #pragma unroll
  for (int j=0;j<KNN_K;++j) tk[j] = 0u;

  for (int t = w; t < htiles; t += 8){
    int mbase = ms*(N>>1) + (t << 6);
    #pragma unroll
    for (int msub=0; msub<4; ++msub){
      int mrow = mbase + msub*16;
      f32x4 acc = {0.f,0.f,0.f,0.f};
      #pragma unroll
      for (int kc=0; kc<C/32; ++kc){
        half8 af = *reinterpret_cast<const half8*>(xh + (size_t)(mrow + c)*C + kc*32 + g*8);
        acc = __builtin_amdgcn_mfma_f32_16x16x32_f16(af, bfrag[kc], acc, 0, 0, 0);
      }
      #pragma unroll
      for (int j=0;j<4;++j){
        int m = mrow + g*4 + j;
        f16 dh = (f16)acc[j];          // einsum output rounds to f16
        f16 mi = dh * (f16)(-2.0f);    // inner = -2*dot
        f16 xm = us2h(xx[m]);
        f16 t1 = (-xm) - mi;           // (-xx[m] - inner)
        f16 pdh = t1 - qxx;            // ... - xx[n]
        insert32(tk, pack_key16(pdh, m));
      }
    }
  }

  {
    unsigned* dst = lists[w*4 + g][c];
    #pragma unroll
    for (int j=0;j<KNN_K;++j) dst[j] = tk[j];
  }
  __syncthreads();

  unsigned tk2[KNN_K];
  if (tid < 128){
    int n = tid >> 3, q = tid & 7;
    #pragma unroll
    for (int j=0;j<KNN_K;++j) tk2[j] = lists[q*4][n][j];
    for (int li=1; li<4; ++li) merge_sorted(tk2, lists[q*4 + li][n]);
  }
  __syncthreads();
  if (tid < 128){
    int n = tid >> 3, q = tid & 7;
    unsigned* dst = lists[q][n];
    #pragma unroll
    for (int j=0;j<KNN_K;++j) dst[j] = tk2[j];
  }
  __syncthreads();
  if (tid < 32){
    int n = tid >> 1, h = tid & 1;
    #pragma unroll
    for (int j=0;j<KNN_K;++j) tk2[j] = lists[h*4][n][j];
    for (int li=1; li<4; ++li) merge_sorted(tk2, lists[h*4 + li][n]);
  }
  __syncthreads();
  if (tid < 32){
    int n = tid >> 1, h = tid & 1;
    unsigned* dst = lists[h][n];
    #pragma unroll
    for (int j=0;j<KNN_K;++j) dst[j] = tk2[j];
  }
  __syncthreads();
  if (tid < 16){
    int n = tid;
    #pragma unroll
    for (int j=0;j<KNN_K;++j) tk2[j] = lists[0][n][j];
    merge_sorted(tk2, lists[1][n]);
    unsigned* dst = pl + ((size_t)ms*N + n0 + n)*KNN_K;
    #pragma unroll
    for (int j=0;j<KNN_K;++j) dst[j] = tk2[j];
  }
}

// merge the 2 m-half partials -> final idx
__global__ __launch_bounds__(256) void knn_final(
    const unsigned* __restrict__ pl, int* __restrict__ idx, int N)
{
  int n = blockIdx.x*256 + threadIdx.x;
  if (n >= N) return;
  unsigned tk[KNN_K];
  const unsigned* p0 = pl + (size_t)n*KNN_K;
  const unsigned* p1 = pl + ((size_t)N + n)*KNN_K;
  #pragma unroll
  for (int j=0;j<KNN_K;++j) tk[j] = p0[j];
  merge_sorted(tk, p1);
  #pragma unroll
  for (int j=0;j<KNN_K;++j)
    idx[(size_t)n*KNN_K + j] = (int)((~tk[j]) & 0xFFFFu);
}

// ---------------- per-point U/V precompute: Ut = t*(Wd X); Vtb = t*((Wc-Wd)X - m) + b ----------------
template<int CIN>
__global__ __launch_bounds__(256) void uv_kernel(
    const float* __restrict__ xCN, const float* __restrict__ W,  // [64][2*CIN]
    const float* __restrict__ bn,
    float* __restrict__ Ut, float* __restrict__ Vtb, int N)
{
  __shared__ float Ws[32][CIN];
  int tid = threadIdx.x;
  int mode = blockIdx.y;      // 0 = U (neighbor term), 1 = V (center term)
  int ob = blockIdx.z * 32;
  for (int i = tid; i < 32*CIN; i += 256){
    int oo = i / CIN, cc = i % CIN;
    float wd = W[(size_t)(ob+oo)*(2*CIN) + cc];
    float wc = W[(size_t)(ob+oo)*(2*CIN) + CIN + cc];
    Ws[oo][cc] = mode ? (wc - wd) : wd;
  }
  __syncthreads();
  int n = blockIdx.x*256 + tid;
  float x[CIN];
  #pragma unroll
  for (int c2=0;c2<CIN;++c2) x[c2] = xCN[(size_t)c2*N + n];
  float acc[32];
  #pragma unroll
  for (int oo=0;oo<32;++oo) acc[oo] = 0.f;
  #pragma unroll 4
  for (int c2=0;c2<CIN;++c2){
    float xv = x[c2];
    #pragma unroll
    for (int oo=0;oo<32;++oo) acc[oo] = fmaf(Ws[oo][c2], xv, acc[oo]);
  }
  float* dst = mode ? Vtb : Ut;
  #pragma unroll
  for (int oo=0;oo<32;++oo){
    int o = ob + oo;
    float t = bn[o] / sqrtf(bn[192+o] + 1e-5f);
    float val = mode ? fmaf(acc[oo] - bn[128+o], t, bn[64+o]) : acc[oo]*t;
    dst[(size_t)n*64 + o] = val;
  }
}

// ---------------- edge conv: e = lrelu(Ut[j]+Vtb[n]); opt f2 = lrelu(bn2(W2 e)); max over k ----------------
// Per-wave LDS broadcast; no barriers needed (each wave reads only its own slice;
// per-wave DS ops execute in order).
template<bool SECOND>
__global__ __launch_bounds__(256) void edge2(
    const float* __restrict__ Ut, const float* __restrict__ Vtb,
    const int* __restrict__ idx,
    const float* __restrict__ W2, const float* __restrict__ bn2,
    float* __restrict__ outCN, unsigned short* __restrict__ outh,
    unsigned short* __restrict__ outxx, int N)
{
  __shared__ float eb[2][4][64];
  int w = threadIdx.x >> 6, o = threadIdx.x & 63;
  float w2r[64]; float t2=0.f,b2=0.f,m2=0.f;
  if (SECOND){
    #pragma unroll
    for (int c4=0;c4<16;++c4){
      float4 wv = *reinterpret_cast<const float4*>(W2 + (size_t)o*64 + c4*4);
      w2r[c4*4+0]=wv.x; w2r[c4*4+1]=wv.y; w2r[c4*4+2]=wv.z; w2r[c4*4+3]=wv.w;
    }
    t2 = bn2[o]/sqrtf(bn2[192+o]+1e-5f); b2 = bn2[64+o]; m2 = bn2[128+o];
  }
  #pragma unroll 1
  for (int q=0;q<2;++q){
    int n = blockIdx.x*8 + w*2 + q;
    float vo = Vtb[(size_t)n*64 + o];
    float best = -INFINITY;
    #pragma unroll 1
    for (int k=0;k<KNN_K;++k){
      int j = idx[(size_t)n*KNN_K + k];
      float e = lrelu(Ut[(size_t)j*64 + o] + vo);
      if (SECOND){
        eb[k&1][w][o] = e;
        const float* ep = eb[k&1][w];
        float s0=0.f,s1=0.f,s2=0.f,s3=0.f;
        #pragma unroll
        for (int c4=0;c4<16;++c4){
          float4 ev = *reinterpret_cast<const float4*>(ep + c4*4);
          s0 = fmaf(w2r[c4*4+0], ev.x, s0);
          s1 = fmaf(w2r[c4*4+1], ev.y, s1);
          s2 = fmaf(w2r[c4*4+2], ev.z, s2);
          s3 = fmaf(w2r[c4*4+3], ev.w, s3);
        }
        float s = (s0+s1)+(s2+s3);
        float f = lrelu(fmaf(s - m2, t2, b2));
        best = fmaxf(best, f);
      } else {
        best = fmaxf(best, e);
      }
    }
    outCN[(size_t)o*N + n] = best;
    if (SECOND){
      f16 h = (f16)best; float hf = (float)h;
      outh[(size_t)n*64 + o] = h2us(h);
      float pe = (float)(f16)(hf*hf);
      float ssum = pe;
      #pragma unroll
      for (int s2s=32;s2s>=1;s2s>>=1) ssum += __shfl_xor(ssum, s2s, 64);
      if (o == 0) outxx[n] = h2us((f16)ssum);
    }
  }
}

// ---------------- fused 1x1-conv v3: o-tile 64 x n-tile 128, LDS-staged weights ----------------
template<bool DOMAX>
__global__ __launch_bounds__(256) void conv_fused(
    const float* __restrict__ WT, int O,
    const float* __restrict__ sA, int cAn,
    const float* __restrict__ sB, int cBn,
    const float* __restrict__ sC, int cCn,
    const float* __restrict__ bnp,
    const float* __restrict__ extra,
    float* __restrict__ out, int N)
{
  __shared__ float ws[32][68];
  int tid = threadIdx.x;
  int ln = tid & 63;
  int og = (tid >> 6) * 16;          // wave-uniform o sub-offset
  int n0 = blockIdx.x*128;
  int ob = blockIdx.y*64;
  int n = n0 + ln*2;
  float a0[16], a1[16];
  #pragma unroll
  for (int i=0;i<16;++i){ a0[i]=0.f; a1[i]=0.f; }

  const float* srcs[3] = {sA, sB, sC};
  int cnts[3] = {cAn, cBn, cCn};
  int cbase = 0;
  #pragma unroll 1
  for (int sidx=0; sidx<3; ++sidx){
    const float* s = srcs[sidx];
    if (!s) continue;
    int cn = cnts[sidx];
    #pragma unroll 1
    for (int c0=0; c0<cn; c0+=32){
      __syncthreads();
      #pragma unroll
      for (int r=0;r<8;++r){
        int i = r*256 + tid;
        int cc = i >> 6, oo = i & 63;
        ws[cc][oo] = WT[(size_t)(cbase+c0+cc)*O + ob + oo];
      }
      __syncthreads();
      #pragma unroll 4
      for (int cc=0; cc<32; ++cc){
        float2 xv = *reinterpret_cast<const float2*>(s + (size_t)(c0+cc)*N + n);
        const float* wr = &ws[cc][og];
        #pragma unroll
        for (int i=0;i<16;++i){
          a0[i] = fmaf(wr[i], xv.x, a0[i]);
          a1[i] = fmaf(wr[i], xv.y, a1[i]);
        }
      }
    }
    cbase += cn;
  }
  #pragma unroll
  for (int i=0;i<16;++i){
    int oG = ob + og + i;
    float t = bnp[oG] / sqrtf(bnp[3*O+oG] + 1e-5f);
    float e = extra ? extra[oG] : 0.f;
    float mm = bnp[2*O+oG], bb = bnp[1*O+oG];
    a0[i] = lrelu(fmaf((a0[i]+e) - mm, t, bb));
    a1[i] = lrelu(fmaf((a1[i]+e) - mm, t, bb));
  }
  if (!DOMAX){
    #pragma unroll
    for (int i=0;i<16;++i){
      float2 st = {a0[i], a1[i]};
      *reinterpret_cast<float2*>(out + (size_t)(ob+og+i)*N + n) = st;
    }
  } else {
    #pragma unroll
    for (int i=0;i<16;++i){
      float v = fmaxf(a0[i], a1[i]);
      #pragma unroll
      for (int s=32;s>=1;s>>=1) v = fmaxf(v, __shfl_xor(v, s, 64));
      if (ln == 0) out[(size_t)(ob+og+i)*gridDim.x + blockIdx.x] = v;
    }
  }
}

__global__ __launch_bounds__(256) void gmax_final(
    const float* __restrict__ gpart, float* __restrict__ g, int O, int P)
{
  int o = blockIdx.x*256 + threadIdx.x;
  if (o >= O) return;
  float m = -INFINITY;
  for (int p=0;p<P;++p) m = fmaxf(m, gpart[(size_t)o*P + p]);
  g[o] = m;
}

// lane-parallel over c with shuffle reduce; one o per wave
__global__ __launch_bounds__(256) void bias7_kernel(
    const float* __restrict__ W7, const float* __restrict__ g, float* __restrict__ b7)
{
  int w = threadIdx.x >> 6, ln = threadIdx.x & 63;
  int o = blockIdx.x*4 + w;
  if (o >= 512) return;
  float a = 0.f;
  #pragma unroll
  for (int c0=0; c0<1024; c0+=64)
    a = fmaf(W7[(size_t)o*1216 + c0 + ln], g[c0 + ln], a);
  #pragma unroll
  for (int s=32;s>=1;s>>=1) a += __shfl_xor(a, s, 64);
  if (ln == 0) b7[o] = a;
}

__global__ __launch_bounds__(256) void w9_kernel(
    const float* __restrict__ W9, const float* __restrict__ h8, float* __restrict__ out, int N)
{
  int n = blockIdx.x*256 + threadIdx.x;
  if (n >= N) return;
  float a0=0.f, a1=0.f, a2=0.f;
  for (int c=0;c<256;++c){
    float xv = h8[(size_t)c*N + n];
    a0 = fmaf(W9[c],       xv, a0);
    a1 = fmaf(W9[256+c],   xv, a1);
    a2 = fmaf(W9[512+c],   xv, a2);
  }
  out[(size_t)n*3+0]=a0; out[(size_t)n*3+1]=a1; out[(size_t)n*3+2]=a2;
}

extern "C" void kernel_launch(void* const* d_in, const int* in_sizes, int n_in,
                              void* d_out, int out_size, void* d_ws, size_t ws_size,
                              hipStream_t stream) {
  const float* curr_pos = (const float*)d_in[0];
  const int*   node_t   = (const int*)  d_in[1];
  const float* W1 = (const float*)d_in[2];
  const float* W2 = (const float*)d_in[3];
  const float* W3 = (const float*)d_in[4];
  const float* W4 = (const float*)d_in[5];
  const float* W5 = (const float*)d_in[6];
  const float* W6 = (const float*)d_in[7];
  const float* W7 = (const float*)d_in[8];
  const float* W8 = (const float*)d_in[9];
  const float* W9 = (const float*)d_in[10];
  const float* bn1 = (const float*)d_in[11];
  const float* bn2 = (const float*)d_in[12];
  const float* bn3 = (const float*)d_in[13];
  const float* bn4 = (const float*)d_in[14];
  const float* bn5 = (const float*)d_in[15];
  const float* bn6 = (const float*)d_in[16];
  const float* bn7 = (const float*)d_in[17];
  const float* bn8 = (const float*)d_in[18];
  float* out = (float*)d_out;

  const int N = in_sizes[0] / 3;

  char* ws = (char*)d_ws;
  size_t off = 0;
  auto A = [&](size_t b){ size_t o = off; off = (o + b + 255) & ~(size_t)255; return o; };

  float* x0CN = (float*)(ws + A((size_t)N*12*4));
  unsigned short* xh0 = (unsigned short*)(ws + A((size_t)N*32*2));
  unsigned short* xx0 = (unsigned short*)(ws + A((size_t)N*2));
  float* x1CN = (float*)(ws + A((size_t)N*64*4));
  unsigned short* xh1 = (unsigned short*)(ws + A((size_t)N*64*2));
  unsigned short* xx1 = (unsigned short*)(ws + A((size_t)N*2));
  float* x2CN = (float*)(ws + A((size_t)N*64*4));
  unsigned short* xh2 = (unsigned short*)(ws + A((size_t)N*64*2));
  unsigned short* xx2 = (unsigned short*)(ws + A((size_t)N*2));
  float* x3CN = (float*)(ws + A((size_t)N*64*4));
  int* idxb = (int*)(ws + A((size_t)N*KNN_K*4));
  unsigned* pl = (unsigned*)(ws + A((size_t)2*N*KNN_K*4));
  float* Ut  = (float*)(ws + A((size_t)N*64*4));
  float* Vtb = (float*)(ws + A((size_t)N*64*4));
  float* w6t  = (float*)(ws + A((size_t)192*1024*4));
  float* w7xt = (float*)(ws + A((size_t)192*512*4));
  float* w8t  = (float*)(ws + A((size_t)512*256*4));
  float* gpart= (float*)(ws + A((size_t)1024*(N/64)*4));
  float* gbuf = (float*)(ws + A((size_t)1024*4));
  float* b7   = (float*)(ws + A((size_t)512*4));

  size_t h7B   = (size_t)512*N*4;
  size_t h8B   = (size_t)256*N*4;
  size_t uniOff = A(((h7B + 255) & ~(size_t)255) + h8B);
  float* h7   = (float*)(ws + uniOff);
  float* h8   = (float*)(ws + uniOff + ((h7B + 255) & ~(size_t)255));
  if (off > ws_size) return;

  dim3 b256(256), b512(512);
  build_x0<<<dim3((N+255)/256), b256, 0, stream>>>(curr_pos, node_t, x0CN, xh0, xx0, N);
  transpose_w<<<dim3((1024*192+255)/256), b256, 0, stream>>>(W6, w6t, 1024, 192, 192, 0);
  transpose_w<<<dim3((512*192+255)/256),  b256, 0, stream>>>(W7, w7xt, 512, 192, 1216, 1024);
  transpose_w<<<dim3((256*512+255)/256),  b256, 0, stream>>>(W8, w8t, 256, 512, 512, 0);

  dim3 gknn(N/16, 2);
  dim3 guv(N/256, 2, 2);
  dim3 gec(N/8);
  dim3 gfin((N+255)/256);

  // round 1
  knn_mfma<32><<<gknn, b512, 0, stream>>>(xh0, xx0, pl, N);
  knn_final<<<gfin, b256, 0, stream>>>(pl, idxb, N);
  uv_kernel<12><<<guv, b256, 0, stream>>>(x0CN, W1, bn1, Ut, Vtb, N);
  edge2<true><<<gec, b256, 0, stream>>>(Ut, Vtb, idxb, W2, bn2, x1CN, xh1, xx1, N);
  // round 2
  knn_mfma<64><<<gknn, b512, 0, stream>>>(xh1, xx1, pl, N);
  knn_final<<<gfin, b256, 0, stream>>>(pl, idxb, N);
  uv_kernel<64><<<guv, b256, 0, stream>>>(x1CN, W3, bn3, Ut, Vtb, N);
  edge2<true><<<gec, b256, 0, stream>>>(Ut, Vtb, idxb, W4, bn4, x2CN, xh2, xx2, N);
  // round 3
  knn_mfma<64><<<gknn, b512, 0, stream>>>(xh2, xx2, pl, N);
  knn_final<<<gfin, b256, 0, stream>>>(pl, idxb, N);
  uv_kernel<64><<<guv, b256, 0, stream>>>(x2CN, W5, bn5, Ut, Vtb, N);
  edge2<false><<<gec, b256, 0, stream>>>(Ut, Vtb, idxb, nullptr, nullptr, x3CN, nullptr, nullptr, N);
  // head
  conv_fused<true><<<dim3(N/128, 16), b256, 0, stream>>>(w6t, 1024, x1CN, 64, x2CN, 64, x3CN, 64, bn6, nullptr, gpart, N);
  gmax_final<<<dim3(4), b256, 0, stream>>>(gpart, gbuf, 1024, N/128);
  bias7_kernel<<<dim3(128), b256, 0, stream>>>(W7, gbuf, b7);
  conv_fused<false><<<dim3(N/128, 8), b256, 0, stream>>>(w7xt, 512, x1CN, 64, x2CN, 64, x3CN, 64, bn7, b7, h7, N);
  conv_fused<false><<<dim3(N/128, 4), b256, 0, stream>>>(w8t, 256, h7, 512, nullptr, 0, nullptr, 0, bn8, nullptr, h8, N);
  w9_kernel<<<gfin, b256, 0, stream>>>(W9, h8, out, N);
}

// Round 11
// 980.994 us; speedup vs baseline: 1.0440x; 1.0440x over previous
//
#include <hip/hip_runtime.h>
#include <hip/hip_bf16.h>

#define KNN_K 20
typedef _Float16 f16;
typedef _Float16 half8 __attribute__((ext_vector_type(8)));
typedef float f32x4 __attribute__((ext_vector_type(4)));

__device__ __forceinline__ float lrelu(float x){ return x >= 0.f ? x : 0.2f*x; }
__device__ __forceinline__ f16 us2h(unsigned short u){ union{unsigned short u; f16 h;} x; x.u=u; return x.h; }
__device__ __forceinline__ unsigned short h2us(f16 h){ union{unsigned short u; f16 h;} x; x.h=h; return x.u; }

// u32 key: [31:16] order-mapped f16 distance (desc), [15:0] ~m (idx asc). Unique, always > 0.
__device__ __forceinline__ unsigned pack_key16(f16 v, int m){
  unsigned u = h2us(v);
  unsigned s = (u & 0x8000u) ? ((~u) & 0xFFFFu) : (u | 0x8000u);
  return (s << 16) | ((~(unsigned)m) & 0xFFFFu);
}

// sorted-desc insert via min/max carry chain: 2 VALU/slot, branchless body.
__device__ __forceinline__ void insert32(unsigned* tk, unsigned key){
  if (key > tk[KNN_K-1]){
    unsigned c = key;
    #pragma unroll
    for (int j=0;j<KNN_K;++j){
      unsigned hi = max(tk[j], c);
      unsigned lo = min(tk[j], c);
      tk[j] = hi;
      c = lo;
    }
  }
}

__device__ __forceinline__ void merge_sorted(unsigned* tk, const unsigned* src){
  #pragma unroll
  for (int j=0;j<KNN_K;++j){
    unsigned key = src[j];
    if (key <= tk[KNN_K-1]) break;
    insert32(tk, key);
  }
}

// ---------------- build x0: CN f32 + padded f16 NC + xx ----------------
__global__ __launch_bounds__(256) void build_x0(
    const float* __restrict__ pos, const int* __restrict__ nt,
    float* __restrict__ x0CN, unsigned short* __restrict__ xh0,
    unsigned short* __restrict__ xx0, int N)
{
  int n = blockIdx.x*256 + threadIdx.x;
  if (n >= N) return;
  float v[12];
  v[0]=pos[n*3+0]; v[1]=pos[n*3+1]; v[2]=pos[n*3+2];
  int t = nt[n];
  #pragma unroll
  for (int c=0;c<9;++c) v[3+c] = (t==c) ? 1.f : 0.f;
  float xa = 0.f;
  #pragma unroll
  for (int c=0;c<12;++c){
    x0CN[(size_t)c*N+n] = v[c];
    f16 h = (f16)v[c];
    float hf = (float)h;
    xh0[(size_t)n*32+c] = h2us(h);
    f16 pe = (f16)(hf*hf);       // elementwise xh*xh rounds to f16
    xa += (float)pe;             // f32 accumulation (jax upcast semantics)
  }
  #pragma unroll
  for (int c=12;c<32;++c) xh0[(size_t)n*32+c] = 0;
  xx0[n] = h2us((f16)xa);
}

// ---------------- weight transpose: dst[c*O+o] = src[o*stride+coff+c] ----------------
__global__ __launch_bounds__(256) void transpose_w(
    const float* __restrict__ src, float* __restrict__ dst, int O, int C, int stride, int coff)
{
  int i = blockIdx.x*256 + threadIdx.x;
  if (i >= O*C) return;
  int o = i / C, c = i % C;
  dst[(size_t)c*O + o] = src[(size_t)o*stride + coff + c];
}

// ---------------- fused MFMA kNN: grid (N/16, 2 m-halves), 512 thr ----------------
// v4: xx staged in LDS (half), running-pointer addressing in the scan loop.
template<int C>
__global__ __launch_bounds__(512) void knn_mfma(
    const unsigned short* __restrict__ xh,  // [N][C] f16 bits
    const unsigned short* __restrict__ xx,  // [N]   f16 bits
    unsigned* __restrict__ pl,              // [2][N][20] partial sorted keys
    int N)
{
  __shared__ unsigned lists[32][16][KNN_K];   // 40960 B
  __shared__ unsigned short xxs[4096];        // 8192 B: this half's xx
  int tid = threadIdx.x;
  int w = tid >> 6, lane = tid & 63;
  int g = lane >> 4, c = lane & 15;
  int n0 = blockIdx.x * 16;
  int ms = blockIdx.y;
  int half0 = ms*(N>>1);
  int htiles = (N >> 7);            // tiles of 64 in this half

  // stage xx (this half): 4096 ushorts = 512 x uint4
  ((uint4*)xxs)[tid] = ((const uint4*)(xx + half0))[tid];

  half8 bfrag[C/32];
  #pragma unroll
  for (int kc=0; kc<C/32; ++kc)
    bfrag[kc] = *reinterpret_cast<const half8*>(xh + (size_t)(n0 + c)*C + kc*32 + g*8);
  f16 qxx = us2h(xx[n0 + c]);
  __syncthreads();

  unsigned tk[KNN_K];
  #pragma unroll
  for (int j=0;j<KNN_K;++j) tk[j] = 0u;

  // running pointers/indices (advance by constants per t-iteration)
  const unsigned short* ap = xh + (size_t)(half0 + w*64 + c)*C + g*8;  // af base (row = mbase + c)
  int ml = w*64 + g*4;                                                 // xxs index base

  for (int t = w; t < htiles; t += 8){
    #pragma unroll
    for (int msub=0; msub<4; ++msub){
      const unsigned short* ap2 = ap + msub*(16*C);
      f32x4 acc = {0.f,0.f,0.f,0.f};
      #pragma unroll
      for (int kc=0; kc<C/32; ++kc){
        half8 af = *reinterpret_cast<const half8*>(ap2 + kc*32);
        acc = __builtin_amdgcn_mfma_f32_16x16x32_f16(af, bfrag[kc], acc, 0, 0, 0);
      }
      #pragma unroll
      for (int j=0;j<4;++j){
        int mloc = ml + msub*16 + j;
        f16 dh = (f16)acc[j];          // einsum output rounds to f16
        f16 mi = dh * (f16)(-2.0f);    // inner = -2*dot
        f16 xm = us2h(xxs[mloc]);
        f16 t1 = (-xm) - mi;           // (-xx[m] - inner)
        f16 pdh = t1 - qxx;            // ... - xx[n]
        insert32(tk, pack_key16(pdh, half0 + mloc));
      }
    }
    ap += (size_t)512*C;
    ml += 512;
  }

  {
    unsigned* dst = lists[w*4 + g][c];
    #pragma unroll
    for (int j=0;j<KNN_K;++j) dst[j] = tk[j];
  }
  __syncthreads();

  unsigned tk2[KNN_K];
  if (tid < 128){
    int n = tid >> 3, q = tid & 7;
    #pragma unroll
    for (int j=0;j<KNN_K;++j) tk2[j] = lists[q*4][n][j];
    for (int li=1; li<4; ++li) merge_sorted(tk2, lists[q*4 + li][n]);
  }
  __syncthreads();
  if (tid < 128){
    int n = tid >> 3, q = tid & 7;
    unsigned* dst = lists[q][n];
    #pragma unroll
    for (int j=0;j<KNN_K;++j) dst[j] = tk2[j];
  }
  __syncthreads();
  if (tid < 32){
    int n = tid >> 1, h = tid & 1;
    #pragma unroll
    for (int j=0;j<KNN_K;++j) tk2[j] = lists[h*4][n][j];
    for (int li=1; li<4; ++li) merge_sorted(tk2, lists[h*4 + li][n]);
  }
  __syncthreads();
  if (tid < 32){
    int n = tid >> 1, h = tid & 1;
    unsigned* dst = lists[h][n];
    #pragma unroll
    for (int j=0;j<KNN_K;++j) dst[j] = tk2[j];
  }
  __syncthreads();
  if (tid < 16){
    int n = tid;
    #pragma unroll
    for (int j=0;j<KNN_K;++j) tk2[j] = lists[0][n][j];
    merge_sorted(tk2, lists[1][n]);
    unsigned* dst = pl + ((size_t)ms*N + n0 + n)*KNN_K;
    #pragma unroll
    for (int j=0;j<KNN_K;++j) dst[j] = tk2[j];
  }
}

// merge the 2 m-half partials -> final idx
__global__ __launch_bounds__(256) void knn_final(
    const unsigned* __restrict__ pl, int* __restrict__ idx, int N)
{
  int n = blockIdx.x*256 + threadIdx.x;
  if (n >= N) return;
  unsigned tk[KNN_K];
  const unsigned* p0 = pl + (size_t)n*KNN_K;
  const unsigned* p1 = pl + ((size_t)N + n)*KNN_K;
  #pragma unroll
  for (int j=0;j<KNN_K;++j) tk[j] = p0[j];
  merge_sorted(tk, p1);
  #pragma unroll
  for (int j=0;j<KNN_K;++j)
    idx[(size_t)n*KNN_K + j] = (int)((~tk[j]) & 0xFFFFu);
}

// ---------------- per-point U/V precompute: Ut = t*(Wd X); Vtb = t*((Wc-Wd)X - m) + b ----------------
template<int CIN>
__global__ __launch_bounds__(256) void uv_kernel(
    const float* __restrict__ xCN, const float* __restrict__ W,  // [64][2*CIN]
    const float* __restrict__ bn,
    float* __restrict__ Ut, float* __restrict__ Vtb, int N)
{
  __shared__ float Ws[32][CIN];
  int tid = threadIdx.x;
  int mode = blockIdx.y;      // 0 = U (neighbor term), 1 = V (center term)
  int ob = blockIdx.z * 32;
  for (int i = tid; i < 32*CIN; i += 256){
    int oo = i / CIN, cc = i % CIN;
    float wd = W[(size_t)(ob+oo)*(2*CIN) + cc];
    float wc = W[(size_t)(ob+oo)*(2*CIN) + CIN + cc];
    Ws[oo][cc] = mode ? (wc - wd) : wd;
  }
  __syncthreads();
  int n = blockIdx.x*256 + tid;
  float x[CIN];
  #pragma unroll
  for (int c2=0;c2<CIN;++c2) x[c2] = xCN[(size_t)c2*N + n];
  float acc[32];
  #pragma unroll
  for (int oo=0;oo<32;++oo) acc[oo] = 0.f;
  #pragma unroll 4
  for (int c2=0;c2<CIN;++c2){
    float xv = x[c2];
    #pragma unroll
    for (int oo=0;oo<32;++oo) acc[oo] = fmaf(Ws[oo][c2], xv, acc[oo]);
  }
  float* dst = mode ? Vtb : Ut;
  #pragma unroll
  for (int oo=0;oo<32;++oo){
    int o = ob + oo;
    float t = bn[o] / sqrtf(bn[192+o] + 1e-5f);
    float val = mode ? fmaf(acc[oo] - bn[128+o], t, bn[64+o]) : acc[oo]*t;
    dst[(size_t)n*64 + o] = val;
  }
}

// ---------------- edge conv: e = lrelu(Ut[j]+Vtb[n]); opt f2 = lrelu(bn2(W2 e)); max over k ----------------
// Per-wave LDS broadcast; no barriers needed (each wave reads only its own slice;
// per-wave DS ops execute in order).
template<bool SECOND>
__global__ __launch_bounds__(256) void edge2(
    const float* __restrict__ Ut, const float* __restrict__ Vtb,
    const int* __restrict__ idx,
    const float* __restrict__ W2, const float* __restrict__ bn2,
    float* __restrict__ outCN, unsigned short* __restrict__ outh,
    unsigned short* __restrict__ outxx, int N)
{
  __shared__ float eb[2][4][64];
  int w = threadIdx.x >> 6, o = threadIdx.x & 63;
  float w2r[64]; float t2=0.f,b2=0.f,m2=0.f;
  if (SECOND){
    #pragma unroll
    for (int c4=0;c4<16;++c4){
      float4 wv = *reinterpret_cast<const float4*>(W2 + (size_t)o*64 + c4*4);
      w2r[c4*4+0]=wv.x; w2r[c4*4+1]=wv.y; w2r[c4*4+2]=wv.z; w2r[c4*4+3]=wv.w;
    }
    t2 = bn2[o]/sqrtf(bn2[192+o]+1e-5f); b2 = bn2[64+o]; m2 = bn2[128+o];
  }
  #pragma unroll 1
  for (int q=0;q<2;++q){
    int n = blockIdx.x*8 + w*2 + q;
    float vo = Vtb[(size_t)n*64 + o];
    float best = -INFINITY;
    #pragma unroll 1
    for (int k=0;k<KNN_K;++k){
      int j = idx[(size_t)n*KNN_K + k];
      float e = lrelu(Ut[(size_t)j*64 + o] + vo);
      if (SECOND){
        eb[k&1][w][o] = e;
        const float* ep = eb[k&1][w];
        float s0=0.f,s1=0.f,s2=0.f,s3=0.f;
        #pragma unroll
        for (int c4=0;c4<16;++c4){
          float4 ev = *reinterpret_cast<const float4*>(ep + c4*4);
          s0 = fmaf(w2r[c4*4+0], ev.x, s0);
          s1 = fmaf(w2r[c4*4+1], ev.y, s1);
          s2 = fmaf(w2r[c4*4+2], ev.z, s2);
          s3 = fmaf(w2r[c4*4+3], ev.w, s3);
        }
        float s = (s0+s1)+(s2+s3);
        float f = lrelu(fmaf(s - m2, t2, b2));
        best = fmaxf(best, f);
      } else {
        best = fmaxf(best, e);
      }
    }
    outCN[(size_t)o*N + n] = best;
    if (SECOND){
      f16 h = (f16)best; float hf = (float)h;
      outh[(size_t)n*64 + o] = h2us(h);
      float pe = (float)(f16)(hf*hf);
      float ssum = pe;
      #pragma unroll
      for (int s2s=32;s2s>=1;s2s>>=1) ssum += __shfl_xor(ssum, s2s, 64);
      if (o == 0) outxx[n] = h2us((f16)ssum);
    }
  }
}

// ---------------- fused 1x1-conv v3: o-tile 64 x n-tile 128, LDS-staged weights ----------------
template<bool DOMAX>
__global__ __launch_bounds__(256) void conv_fused(
    const float* __restrict__ WT, int O,
    const float* __restrict__ sA, int cAn,
    const float* __restrict__ sB, int cBn,
    const float* __restrict__ sC, int cCn,
    const float* __restrict__ bnp,
    const float* __restrict__ extra,
    float* __restrict__ out, int N)
{
  __shared__ float ws[32][68];
  int tid = threadIdx.x;
  int ln = tid & 63;
  int og = (tid >> 6) * 16;          // wave-uniform o sub-offset
  int n0 = blockIdx.x*128;
  int ob = blockIdx.y*64;
  int n = n0 + ln*2;
  float a0[16], a1[16];
  #pragma unroll
  for (int i=0;i<16;++i){ a0[i]=0.f; a1[i]=0.f; }

  const float* srcs[3] = {sA, sB, sC};
  int cnts[3] = {cAn, cBn, cCn};
  int cbase = 0;
  #pragma unroll 1
  for (int sidx=0; sidx<3; ++sidx){
    const float* s = srcs[sidx];
    if (!s) continue;
    int cn = cnts[sidx];
    #pragma unroll 1
    for (int c0=0; c0<cn; c0+=32){
      __syncthreads();
      #pragma unroll
      for (int r=0;r<8;++r){
        int i = r*256 + tid;
        int cc = i >> 6, oo = i & 63;
        ws[cc][oo] = WT[(size_t)(cbase+c0+cc)*O + ob + oo];
      }
      __syncthreads();
      #pragma unroll 4
      for (int cc=0; cc<32; ++cc){
        float2 xv = *reinterpret_cast<const float2*>(s + (size_t)(c0+cc)*N + n);
        const float* wr = &ws[cc][og];
        #pragma unroll
        for (int i=0;i<16;++i){
          a0[i] = fmaf(wr[i], xv.x, a0[i]);
          a1[i] = fmaf(wr[i], xv.y, a1[i]);
        }
      }
    }
    cbase += cn;
  }
  #pragma unroll
  for (int i=0;i<16;++i){
    int oG = ob + og + i;
    float t = bnp[oG] / sqrtf(bnp[3*O+oG] + 1e-5f);
    float e = extra ? extra[oG] : 0.f;
    float mm = bnp[2*O+oG], bb = bnp[1*O+oG];
    a0[i] = lrelu(fmaf((a0[i]+e) - mm, t, bb));
    a1[i] = lrelu(fmaf((a1[i]+e) - mm, t, bb));
  }
  if (!DOMAX){
    #pragma unroll
    for (int i=0;i<16;++i){
      float2 st = {a0[i], a1[i]};
      *reinterpret_cast<float2*>(out + (size_t)(ob+og+i)*N + n) = st;
    }
  } else {
    #pragma unroll
    for (int i=0;i<16;++i){
      float v = fmaxf(a0[i], a1[i]);
      #pragma unroll
      for (int s=32;s>=1;s>>=1) v = fmaxf(v, __shfl_xor(v, s, 64));
      if (ln == 0) out[(size_t)(ob+og+i)*gridDim.x + blockIdx.x] = v;
    }
  }
}

__global__ __launch_bounds__(256) void gmax_final(
    const float* __restrict__ gpart, float* __restrict__ g, int O, int P)
{
  int o = blockIdx.x*256 + threadIdx.x;
  if (o >= O) return;
  float m = -INFINITY;
  for (int p=0;p<P;++p) m = fmaxf(m, gpart[(size_t)o*P + p]);
  g[o] = m;
}

// lane-parallel over c with shuffle reduce; one o per wave
__global__ __launch_bounds__(256) void bias7_kernel(
    const float* __restrict__ W7, const float* __restrict__ g, float* __restrict__ b7)
{
  int w = threadIdx.x >> 6, ln = threadIdx.x & 63;
  int o = blockIdx.x*4 + w;
  if (o >= 512) return;
  float a = 0.f;
  #pragma unroll
  for (int c0=0; c0<1024; c0+=64)
    a = fmaf(W7[(size_t)o*1216 + c0 + ln], g[c0 + ln], a);
  #pragma unroll
  for (int s=32;s>=1;s>>=1) a += __shfl_xor(a, s, 64);
  if (ln == 0) b7[o] = a;
}

__global__ __launch_bounds__(256) void w9_kernel(
    const float* __restrict__ W9, const float* __restrict__ h8, float* __restrict__ out, int N)
{
  int n = blockIdx.x*256 + threadIdx.x;
  if (n >= N) return;
  float a0=0.f, a1=0.f, a2=0.f;
  for (int c=0;c<256;++c){
    float xv = h8[(size_t)c*N + n];
    a0 = fmaf(W9[c],       xv, a0);
    a1 = fmaf(W9[256+c],   xv, a1);
    a2 = fmaf(W9[512+c],   xv, a2);
  }
  out[(size_t)n*3+0]=a0; out[(size_t)n*3+1]=a1; out[(size_t)n*3+2]=a2;
}

extern "C" void kernel_launch(void* const* d_in, const int* in_sizes, int n_in,
                              void* d_out, int out_size, void* d_ws, size_t ws_size,
                              hipStream_t stream) {
  const float* curr_pos = (const float*)d_in[0];
  const int*   node_t   = (const int*)  d_in[1];
  const float* W1 = (const float*)d_in[2];
  const float* W2 = (const float*)d_in[3];
  const float* W3 = (const float*)d_in[4];
  const float* W4 = (const float*)d_in[5];
  const float* W5 = (const float*)d_in[6];
  const float* W6 = (const float*)d_in[7];
  const float* W7 = (const float*)d_in[8];
  const float* W8 = (const float*)d_in[9];
  const float* W9 = (const float*)d_in[10];
  const float* bn1 = (const float*)d_in[11];
  const float* bn2 = (const float*)d_in[12];
  const float* bn3 = (const float*)d_in[13];
  const float* bn4 = (const float*)d_in[14];
  const float* bn5 = (const float*)d_in[15];
  const float* bn6 = (const float*)d_in[16];
  const float* bn7 = (const float*)d_in[17];
  const float* bn8 = (const float*)d_in[18];
  float* out = (float*)d_out;

  const int N = in_sizes[0] / 3;

  char* ws = (char*)d_ws;
  size_t off = 0;
  auto A = [&](size_t b){ size_t o = off; off = (o + b + 255) & ~(size_t)255; return o; };

  float* x0CN = (float*)(ws + A((size_t)N*12*4));
  unsigned short* xh0 = (unsigned short*)(ws + A((size_t)N*32*2));
  unsigned short* xx0 = (unsigned short*)(ws + A((size_t)N*2));
  float* x1CN = (float*)(ws + A((size_t)N*64*4));
  unsigned short* xh1 = (unsigned short*)(ws + A((size_t)N*64*2));
  unsigned short* xx1 = (unsigned short*)(ws + A((size_t)N*2));
  float* x2CN = (float*)(ws + A((size_t)N*64*4));
  unsigned short* xh2 = (unsigned short*)(ws + A((size_t)N*64*2));
  unsigned short* xx2 = (unsigned short*)(ws + A((size_t)N*2));
  float* x3CN = (float*)(ws + A((size_t)N*64*4));
  int* idxb = (int*)(ws + A((size_t)N*KNN_K*4));
  unsigned* pl = (unsigned*)(ws + A((size_t)2*N*KNN_K*4));
  float* Ut  = (float*)(ws + A((size_t)N*64*4));
  float* Vtb = (float*)(ws + A((size_t)N*64*4));
  float* w6t  = (float*)(ws + A((size_t)192*1024*4));
  float* w7xt = (float*)(ws + A((size_t)192*512*4));
  float* w8t  = (float*)(ws + A((size_t)512*256*4));
  float* gpart= (float*)(ws + A((size_t)1024*(N/64)*4));
  float* gbuf = (float*)(ws + A((size_t)1024*4));
  float* b7   = (float*)(ws + A((size_t)512*4));

  size_t h7B   = (size_t)512*N*4;
  size_t h8B   = (size_t)256*N*4;
  size_t uniOff = A(((h7B + 255) & ~(size_t)255) + h8B);
  float* h7   = (float*)(ws + uniOff);
  float* h8   = (float*)(ws + uniOff + ((h7B + 255) & ~(size_t)255));
  if (off > ws_size) return;

  dim3 b256(256), b512(512);
  build_x0<<<dim3((N+255)/256), b256, 0, stream>>>(curr_pos, node_t, x0CN, xh0, xx0, N);
  transpose_w<<<dim3((1024*192+255)/256), b256, 0, stream>>>(W6, w6t, 1024, 192, 192, 0);
  transpose_w<<<dim3((512*192+255)/256),  b256, 0, stream>>>(W7, w7xt, 512, 192, 1216, 1024);
  transpose_w<<<dim3((256*512+255)/256),  b256, 0, stream>>>(W8, w8t, 256, 512, 512, 0);

  dim3 gknn(N/16, 2);
  dim3 guv(N/256, 2, 2);
  dim3 gec(N/8);
  dim3 gfin((N+255)/256);

  // round 1
  knn_mfma<32><<<gknn, b512, 0, stream>>>(xh0, xx0, pl, N);
  knn_final<<<gfin, b256, 0, stream>>>(pl, idxb, N);
  uv_kernel<12><<<guv, b256, 0, stream>>>(x0CN, W1, bn1, Ut, Vtb, N);
  edge2<true><<<gec, b256, 0, stream>>>(Ut, Vtb, idxb, W2, bn2, x1CN, xh1, xx1, N);
  // round 2
  knn_mfma<64><<<gknn, b512, 0, stream>>>(xh1, xx1, pl, N);
  knn_final<<<gfin, b256, 0, stream>>>(pl, idxb, N);
  uv_kernel<64><<<guv, b256, 0, stream>>>(x1CN, W3, bn3, Ut, Vtb, N);
  edge2<true><<<gec, b256, 0, stream>>>(Ut, Vtb, idxb, W4, bn4, x2CN, xh2, xx2, N);
  // round 3
  knn_mfma<64><<<gknn, b512, 0, stream>>>(xh2, xx2, pl, N);
  knn_final<<<gfin, b256, 0, stream>>>(pl, idxb, N);
  uv_kernel<64><<<guv, b256, 0, stream>>>(x2CN, W5, bn5, Ut, Vtb, N);
  edge2<false><<<gec, b256, 0, stream>>>(Ut, Vtb, idxb, nullptr, nullptr, x3CN, nullptr, nullptr, N);
  // head
  conv_fused<true><<<dim3(N/128, 16), b256, 0, stream>>>(w6t, 1024, x1CN, 64, x2CN, 64, x3CN, 64, bn6, nullptr, gpart, N);
  gmax_final<<<dim3(4), b256, 0, stream>>>(gpart, gbuf, 1024, N/128);
  bias7_kernel<<<dim3(128), b256, 0, stream>>>(W7, gbuf, b7);
  conv_fused<false><<<dim3(N/128, 8), b256, 0, stream>>>(w7xt, 512, x1CN, 64, x2CN, 64, x3CN, 64, bn7, b7, h7, N);
  conv_fused<false><<<dim3(N/128, 4), b256, 0, stream>>>(w8t, 256, h7, 512, nullptr, 0, nullptr, 0, bn8, nullptr, h8, N);
  w9_kernel<<<gfin, b256, 0, stream>>>(W9, h8, out, N);
}

// Round 13
// 847.725 us; speedup vs baseline: 1.2082x; 1.1572x over previous
//
#include <hip/hip_runtime.h>
#include <hip/hip_bf16.h>

#define KNN_K 20
typedef _Float16 f16;
typedef _Float16 half8 __attribute__((ext_vector_type(8)));
typedef float f32x4 __attribute__((ext_vector_type(4)));

__device__ __forceinline__ float lrelu(float x){ return x >= 0.f ? x : 0.2f*x; }
__device__ __forceinline__ f16 us2h(unsigned short u){ union{unsigned short u; f16 h;} x; x.u=u; return x.h; }
__device__ __forceinline__ unsigned short h2us(f16 h){ union{unsigned short u; f16 h;} x; x.h=h; return x.u; }

// u32 key: [31:16] order-mapped f16 distance (desc), [15:0] ~m (idx asc). Unique, always > 0.
__device__ __forceinline__ unsigned pack_key16(f16 v, int m){
  unsigned u = h2us(v);
  unsigned s = (u & 0x8000u) ? ((~u) & 0xFFFFu) : (u | 0x8000u);
  return (s << 16) | ((~(unsigned)m) & 0xFFFFu);
}

// UNGUARDED sorted-desc insert: min/max carry chain. A key below tk[19]
// bubbles through and falls off the end (tk unchanged) -- semantically safe.
// Acceptance is wave-coherent (P(any lane accepts) ~= 1), so the guard only
// added exec-mask/branch overhead.
__device__ __forceinline__ void insert_nc(unsigned* tk, unsigned key){
  unsigned c = key;
  #pragma unroll
  for (int j=0;j<KNN_K;++j){
    unsigned hi = max(tk[j], c);
    unsigned lo = min(tk[j], c);
    tk[j] = hi;
    c = lo;
  }
}

// guarded version for sparse merge phases
__device__ __forceinline__ void insert32(unsigned* tk, unsigned key){
  if (key > tk[KNN_K-1]) insert_nc(tk, key);
}

__device__ __forceinline__ void merge_sorted(unsigned* tk, const unsigned* src){
  #pragma unroll
  for (int j=0;j<KNN_K;++j){
    unsigned key = src[j];
    if (key <= tk[KNN_K-1]) break;
    insert_nc(tk, key);
  }
}

// ---------------- prep0: build x0 + all weight transposes (fused) ----------------
__global__ __launch_bounds__(256) void prep0(
    const float* __restrict__ pos, const int* __restrict__ nt,
    float* __restrict__ x0CN, unsigned short* __restrict__ xh0,
    unsigned short* __restrict__ xx0, int N,
    const float* __restrict__ W6, float* __restrict__ w6t,
    const float* __restrict__ W7, float* __restrict__ w7xt,
    const float* __restrict__ W8, float* __restrict__ w8t)
{
  int b = blockIdx.x, tid = threadIdx.x;
  int nb0 = (N + 255) >> 8;
  if (b < nb0){
    int n = b*256 + tid;
    if (n >= N) return;
    float v[12];
    v[0]=pos[n*3+0]; v[1]=pos[n*3+1]; v[2]=pos[n*3+2];
    int t = nt[n];
    #pragma unroll
    for (int c=0;c<9;++c) v[3+c] = (t==c) ? 1.f : 0.f;
    float xa = 0.f;
    #pragma unroll
    for (int c=0;c<12;++c){
      x0CN[(size_t)c*N+n] = v[c];
      f16 h = (f16)v[c];
      float hf = (float)h;
      xh0[(size_t)n*32+c] = h2us(h);
      f16 pe = (f16)(hf*hf);       // elementwise xh*xh rounds to f16
      xa += (float)pe;             // f32 accumulation (jax upcast semantics)
    }
    #pragma unroll
    for (int c=12;c<32;++c) xh0[(size_t)n*32+c] = 0;
    xx0[n] = h2us((f16)xa);
    return;
  }
  b -= nb0;
  if (b < 768){                      // W6: [1024][192] -> w6t[c*1024+o]
    int i = b*256 + tid;
    int o = i / 192, c = i % 192;
    w6t[(size_t)c*1024 + o] = W6[(size_t)o*192 + c];
    return;
  }
  b -= 768;
  if (b < 384){                      // W7 x-part: [512][1216], coff 1024, C=192
    int i = b*256 + tid;
    int o = i / 192, c = i % 192;
    w7xt[(size_t)c*512 + o] = W7[(size_t)o*1216 + 1024 + c];
    return;
  }
  b -= 384;
  {                                  // W8: [256][512]
    int i = b*256 + tid;
    int o = i / 512, c = i % 512;
    w8t[(size_t)c*256 + o] = W8[(size_t)o*512 + c];
  }
}

// ---------------- fused MFMA kNN: grid (N/16, 2 m-halves), 512 thr ----------------
template<int C>
__global__ __launch_bounds__(512) void knn_mfma(
    const unsigned short* __restrict__ xh,  // [N][C] f16 bits
    const unsigned short* __restrict__ xx,  // [N]   f16 bits
    unsigned* __restrict__ pl,              // [2][N][20] partial sorted keys
    int N)
{
  __shared__ unsigned lists[32][16][KNN_K];   // 40960 B
  __shared__ unsigned short xxs[4096];        // 8192 B: this half's xx
  int tid = threadIdx.x;
  int w = tid >> 6, lane = tid & 63;
  int g = lane >> 4, c = lane & 15;
  int n0 = blockIdx.x * 16;
  int ms = blockIdx.y;
  int half0 = ms*(N>>1);
  int htiles = (N >> 7);            // tiles of 64 in this half

  // stage xx (this half): 4096 ushorts = 512 x uint4
  ((uint4*)xxs)[tid] = ((const uint4*)(xx + half0))[tid];

  half8 bfrag[C/32];
  #pragma unroll
  for (int kc=0; kc<C/32; ++kc)
    bfrag[kc] = *reinterpret_cast<const half8*>(xh + (size_t)(n0 + c)*C + kc*32 + g*8);
  f16 qxx = us2h(xx[n0 + c]);
  __syncthreads();

  unsigned tk[KNN_K];
  #pragma unroll
  for (int j=0;j<KNN_K;++j) tk[j] = 0u;

  // running pointers/indices (advance by constants per t-iteration)
  const unsigned short* ap = xh + (size_t)(half0 + w*64 + c)*C + g*8;
  int ml = w*64 + g*4;

  for (int t = w; t < htiles; t += 8){
    #pragma unroll
    for (int msub=0; msub<4; ++msub){
      const unsigned short* ap2 = ap + msub*(16*C);
      f32x4 acc = {0.f,0.f,0.f,0.f};
      #pragma unroll
      for (int kc=0; kc<C/32; ++kc){
        half8 af = *reinterpret_cast<const half8*>(ap2 + kc*32);
        acc = __builtin_amdgcn_mfma_f32_16x16x32_f16(af, bfrag[kc], acc, 0, 0, 0);
      }
      #pragma unroll
      for (int j=0;j<4;++j){
        int mloc = ml + msub*16 + j;
        f16 dh = (f16)acc[j];          // einsum output rounds to f16
        f16 mi = dh * (f16)(-2.0f);    // inner = -2*dot
        f16 xm = us2h(xxs[mloc]);
        f16 t1 = (-xm) - mi;           // (-xx[m] - inner)
        f16 pdh = t1 - qxx;            // ... - xx[n]
        insert_nc(tk, pack_key16(pdh, half0 + mloc));
      }
    }
    ap += (size_t)512*C;
    ml += 512;
  }

  {
    unsigned* dst = lists[w*4 + g][c];
    #pragma unroll
    for (int j=0;j<KNN_K;++j) dst[j] = tk[j];
  }
  __syncthreads();

  unsigned tk2[KNN_K];
  if (tid < 128){
    int n = tid >> 3, q = tid & 7;
    #pragma unroll
    for (int j=0;j<KNN_K;++j) tk2[j] = lists[q*4][n][j];
    for (int li=1; li<4; ++li) merge_sorted(tk2, lists[q*4 + li][n]);
  }
  __syncthreads();
  if (tid < 128){
    int n = tid >> 3, q = tid & 7;
    unsigned* dst = lists[q][n];
    #pragma unroll
    for (int j=0;j<KNN_K;++j) dst[j] = tk2[j];
  }
  __syncthreads();
  if (tid < 32){
    int n = tid >> 1, h = tid & 1;
    #pragma unroll
    for (int j=0;j<KNN_K;++j) tk2[j] = lists[h*4][n][j];
    for (int li=1; li<4; ++li) merge_sorted(tk2, lists[h*4 + li][n]);
  }
  __syncthreads();
  if (tid < 32){
    int n = tid >> 1, h = tid & 1;
    unsigned* dst = lists[h][n];
    #pragma unroll
    for (int j=0;j<KNN_K;++j) dst[j] = tk2[j];
  }
  __syncthreads();
  if (tid < 16){
    int n = tid;
    #pragma unroll
    for (int j=0;j<KNN_K;++j) tk2[j] = lists[0][n][j];
    merge_sorted(tk2, lists[1][n]);
    unsigned* dst = pl + ((size_t)ms*N + n0 + n)*KNN_K;
    #pragma unroll
    for (int j=0;j<KNN_K;++j) dst[j] = tk2[j];
  }
}

// ---------------- fused per-round prep: knn_final (2-half merge) + U/V precompute ----------------
template<int CIN>
__global__ __launch_bounds__(256) void prep_knn_uv(
    const unsigned* __restrict__ pl, int* __restrict__ idx,
    const float* __restrict__ xCN, const float* __restrict__ W,  // [64][2*CIN]
    const float* __restrict__ bn,
    float* __restrict__ Ut, float* __restrict__ Vtb, int N)
{
  __shared__ float Ws[32][CIN];
  int b = blockIdx.x, tid = threadIdx.x;
  int nfb = N >> 8;
  if (b < nfb){
    // ---- knn_final ----
    int n = b*256 + tid;
    if (n >= N) return;
    unsigned tk[KNN_K];
    const unsigned* p0 = pl + (size_t)n*KNN_K;
    const unsigned* p1 = pl + ((size_t)N + n)*KNN_K;
    #pragma unroll
    for (int j=0;j<KNN_K;++j) tk[j] = p0[j];
    merge_sorted(tk, p1);
    #pragma unroll
    for (int j=0;j<KNN_K;++j)
      idx[(size_t)n*KNN_K + j] = (int)((~tk[j]) & 0xFFFFu);
    return;
  }
  // ---- uv ----
  int u = b - nfb;              // [0, 4*nfb)
  int nb = u % nfb;
  int r = u / nfb;
  int mode = r & 1;             // 0 = U (neighbor term), 1 = V (center term)
  int ob = (r >> 1) * 32;
  for (int i = tid; i < 32*CIN; i += 256){
    int oo = i / CIN, cc = i % CIN;
    float wd = W[(size_t)(ob+oo)*(2*CIN) + cc];
    float wc = W[(size_t)(ob+oo)*(2*CIN) + CIN + cc];
    Ws[oo][cc] = mode ? (wc - wd) : wd;
  }
  __syncthreads();
  int n = nb*256 + tid;
  float x[CIN];
  #pragma unroll
  for (int c2=0;c2<CIN;++c2) x[c2] = xCN[(size_t)c2*N + n];
  float acc[32];
  #pragma unroll
  for (int oo=0;oo<32;++oo) acc[oo] = 0.f;
  #pragma unroll 4
  for (int c2=0;c2<CIN;++c2){
    float xv = x[c2];
    #pragma unroll
    for (int oo=0;oo<32;++oo) acc[oo] = fmaf(Ws[oo][c2], xv, acc[oo]);
  }
  float* dst = mode ? Vtb : Ut;
  #pragma unroll
  for (int oo=0;oo<32;++oo){
    int o = ob + oo;
    float t = bn[o] / sqrtf(bn[192+o] + 1e-5f);
    float val = mode ? fmaf(acc[oo] - bn[128+o], t, bn[64+o]) : acc[oo]*t;
    dst[(size_t)n*64 + o] = val;
  }
}

// ---------------- edge conv: e = lrelu(Ut[j]+Vtb[n]); opt f2 = lrelu(bn2(W2 e)); max over k ----------------
template<bool SECOND>
__global__ __launch_bounds__(256) void edge2(
    const float* __restrict__ Ut, const float* __restrict__ Vtb,
    const int* __restrict__ idx,
    const float* __restrict__ W2, const float* __restrict__ bn2,
    float* __restrict__ outCN, unsigned short* __restrict__ outh,
    unsigned short* __restrict__ outxx, int N)
{
  __shared__ float eb[2][4][64];
  int w = threadIdx.x >> 6, o = threadIdx.x & 63;
  float w2r[64]; float t2=0.f,b2=0.f,m2=0.f;
  if (SECOND){
    #pragma unroll
    for (int c4=0;c4<16;++c4){
      float4 wv = *reinterpret_cast<const float4*>(W2 + (size_t)o*64 + c4*4);
      w2r[c4*4+0]=wv.x; w2r[c4*4+1]=wv.y; w2r[c4*4+2]=wv.z; w2r[c4*4+3]=wv.w;
    }
    t2 = bn2[o]/sqrtf(bn2[192+o]+1e-5f); b2 = bn2[64+o]; m2 = bn2[128+o];
  }
  #pragma unroll 1
  for (int q=0;q<2;++q){
    int n = blockIdx.x*8 + w*2 + q;
    float vo = Vtb[(size_t)n*64 + o];
    float best = -INFINITY;
    #pragma unroll 1
    for (int k=0;k<KNN_K;++k){
      int j = idx[(size_t)n*KNN_K + k];
      float e = lrelu(Ut[(size_t)j*64 + o] + vo);
      if (SECOND){
        eb[k&1][w][o] = e;
        const float* ep = eb[k&1][w];
        float s0=0.f,s1=0.f,s2=0.f,s3=0.f;
        #pragma unroll
        for (int c4=0;c4<16;++c4){
          float4 ev = *reinterpret_cast<const float4*>(ep + c4*4);
          s0 = fmaf(w2r[c4*4+0], ev.x, s0);
          s1 = fmaf(w2r[c4*4+1], ev.y, s1);
          s2 = fmaf(w2r[c4*4+2], ev.z, s2);
          s3 = fmaf(w2r[c4*4+3], ev.w, s3);
        }
        float s = (s0+s1)+(s2+s3);
        float f = lrelu(fmaf(s - m2, t2, b2));
        best = fmaxf(best, f);
      } else {
        best = fmaxf(best, e);
      }
    }
    outCN[(size_t)o*N + n] = best;
    if (SECOND){
      f16 h = (f16)best; float hf = (float)h;
      outh[(size_t)n*64 + o] = h2us(h);
      float pe = (float)(f16)(hf*hf);
      float ssum = pe;
      #pragma unroll
      for (int s2s=32;s2s>=1;s2s>>=1) ssum += __shfl_xor(ssum, s2s, 64);
      if (o == 0) outxx[n] = h2us((f16)ssum);
    }
  }
}

// ---------------- fused 1x1-conv v3: o-tile 64 x n-tile 128, LDS-staged weights ----------------
template<bool DOMAX>
__global__ __launch_bounds__(256) void conv_fused(
    const float* __restrict__ WT, int O,
    const float* __restrict__ sA, int cAn,
    const float* __restrict__ sB, int cBn,
    const float* __restrict__ sC, int cCn,
    const float* __restrict__ bnp,
    const float* __restrict__ extra,
    float* __restrict__ out, int N)
{
  __shared__ float ws[32][68];
  int tid = threadIdx.x;
  int ln = tid & 63;
  int og = (tid >> 6) * 16;          // wave-uniform o sub-offset
  int n0 = blockIdx.x*128;
  int ob = blockIdx.y*64;
  int n = n0 + ln*2;
  float a0[16], a1[16];
  #pragma unroll
  for (int i=0;i<16;++i){ a0[i]=0.f; a1[i]=0.f; }

  const float* srcs[3] = {sA, sB, sC};
  int cnts[3] = {cAn, cBn, cCn};
  int cbase = 0;
  #pragma unroll 1
  for (int sidx=0; sidx<3; ++sidx){
    const float* s = srcs[sidx];
    if (!s) continue;
    int cn = cnts[sidx];
    #pragma unroll 1
    for (int c0=0; c0<cn; c0+=32){
      __syncthreads();
      #pragma unroll
      for (int r=0;r<8;++r){
        int i = r*256 + tid;
        int cc = i >> 6, oo = i & 63;
        ws[cc][oo] = WT[(size_t)(cbase+c0+cc)*O + ob + oo];
      }
      __syncthreads();
      #pragma unroll 4
      for (int cc=0; cc<32; ++cc){
        float2 xv = *reinterpret_cast<const float2*>(s + (size_t)(c0+cc)*N + n);
        const float* wr = &ws[cc][og];
        #pragma unroll
        for (int i=0;i<16;++i){
          a0[i] = fmaf(wr[i], xv.x, a0[i]);
          a1[i] = fmaf(wr[i], xv.y, a1[i]);
        }
      }
    }
    cbase += cn;
  }
  #pragma unroll
  for (int i=0;i<16;++i){
    int oG = ob + og + i;
    float t = bnp[oG] / sqrtf(bnp[3*O+oG] + 1e-5f);
    float e = extra ? extra[oG] : 0.f;
    float mm = bnp[2*O+oG], bb = bnp[1*O+oG];
    a0[i] = lrelu(fmaf((a0[i]+e) - mm, t, bb));
    a1[i] = lrelu(fmaf((a1[i]+e) - mm, t, bb));
  }
  if (!DOMAX){
    #pragma unroll
    for (int i=0;i<16;++i){
      float2 st = {a0[i], a1[i]};
      *reinterpret_cast<float2*>(out + (size_t)(ob+og+i)*N + n) = st;
    }
  } else {
    #pragma unroll
    for (int i=0;i<16;++i){
      float v = fmaxf(a0[i], a1[i]);
      #pragma unroll
      for (int s=32;s>=1;s>>=1) v = fmaxf(v, __shfl_xor(v, s, 64));
      if (ln == 0) out[(size_t)(ob+og+i)*gridDim.x + blockIdx.x] = v;
    }
  }
}

__global__ __launch_bounds__(256) void gmax_final(
    const float* __restrict__ gpart, float* __restrict__ g, int O, int P)
{
  int o = blockIdx.x*256 + threadIdx.x;
  if (o >= O) return;
  float m = -INFINITY;
  for (int p=0;p<P;++p) m = fmaxf(m, gpart[(size_t)o*P + p]);
  g[o] = m;
}

// lane-parallel over c with shuffle reduce; one o per wave
__global__ __launch_bounds__(256) void bias7_kernel(
    const float* __restrict__ W7, const float* __restrict__ g, float* __restrict__ b7)
{
  int w = threadIdx.x >> 6, ln = threadIdx.x & 63;
  int o = blockIdx.x*4 + w;
  if (o >= 512) return;
  float a = 0.f;
  #pragma unroll
  for (int c0=0; c0<1024; c0+=64)
    a = fmaf(W7[(size_t)o*1216 + c0 + ln], g[c0 + ln], a);
  #pragma unroll
  for (int s=32;s>=1;s>>=1) a += __shfl_xor(a, s, 64);
  if (ln == 0) b7[o] = a;
}

__global__ __launch_bounds__(256) void w9_kernel(
    const float* __restrict__ W9, const float* __restrict__ h8, float* __restrict__ out, int N)
{
  int n = blockIdx.x*256 + threadIdx.x;
  if (n >= N) return;
  float a0=0.f, a1=0.f, a2=0.f;
  for (int c=0;c<256;++c){
    float xv = h8[(size_t)c*N + n];
    a0 = fmaf(W9[c],       xv, a0);
    a1 = fmaf(W9[256+c],   xv, a1);
    a2 = fmaf(W9[512+c],   xv, a2);
  }
  out[(size_t)n*3+0]=a0; out[(size_t)n*3+1]=a1; out[(size_t)n*3+2]=a2;
}

extern "C" void kernel_launch(void* const* d_in, const int* in_sizes, int n_in,
                              void* d_out, int out_size, void* d_ws, size_t ws_size,
                              hipStream_t stream) {
  const float* curr_pos = (const float*)d_in[0];
  const int*   node_t   = (const int*)  d_in[1];
  const float* W1 = (const float*)d_in[2];
  const float* W2 = (const float*)d_in[3];
  const float* W3 = (const float*)d_in[4];
  const float* W4 = (const float*)d_in[5];
  const float* W5 = (const float*)d_in[6];
  const float* W6 = (const float*)d_in[7];
  const float* W7 = (const float*)d_in[8];
  const float* W8 = (const float*)d_in[9];
  const float* W9 = (const float*)d_in[10];
  const float* bn1 = (const float*)d_in[11];
  const float* bn2 = (const float*)d_in[12];
  const float* bn3 = (const float*)d_in[13];
  const float* bn4 = (const float*)d_in[14];
  const float* bn5 = (const float*)d_in[15];
  const float* bn6 = (const float*)d_in[16];
  const float* bn7 = (const float*)d_in[17];
  const float* bn8 = (const float*)d_in[18];
  float* out = (float*)d_out;

  const int N = in_sizes[0] / 3;

  char* ws = (char*)d_ws;
  size_t off = 0;
  auto A = [&](size_t b){ size_t o = off; off = (o + b + 255) & ~(size_t)255; return o; };

  float* x0CN = (float*)(ws + A((size_t)N*12*4));
  unsigned short* xh0 = (unsigned short*)(ws + A((size_t)N*32*2));
  unsigned short* xx0 = (unsigned short*)(ws + A((size_t)N*2));
  float* x1CN = (float*)(ws + A((size_t)N*64*4));
  unsigned short* xh1 = (unsigned short*)(ws + A((size_t)N*64*2));
  unsigned short* xx1 = (unsigned short*)(ws + A((size_t)N*2));
  float* x2CN = (float*)(ws + A((size_t)N*64*4));
  unsigned short* xh2 = (unsigned short*)(ws + A((size_t)N*64*2));
  unsigned short* xx2 = (unsigned short*)(ws + A((size_t)N*2));
  float* x3CN = (float*)(ws + A((size_t)N*64*4));
  int* idxb = (int*)(ws + A((size_t)N*KNN_K*4));
  unsigned* pl = (unsigned*)(ws + A((size_t)2*N*KNN_K*4));
  float* Ut  = (float*)(ws + A((size_t)N*64*4));
  float* Vtb = (float*)(ws + A((size_t)N*64*4));
  float* w6t  = (float*)(ws + A((size_t)192*1024*4));
  float* w7xt = (float*)(ws + A((size_t)192*512*4));
  float* w8t  = (float*)(ws + A((size_t)512*256*4));
  float* gpart= (float*)(ws + A((size_t)1024*(N/64)*4));
  float* gbuf = (float*)(ws + A((size_t)1024*4));
  float* b7   = (float*)(ws + A((size_t)512*4));

  size_t h7B   = (size_t)512*N*4;
  size_t h8B   = (size_t)256*N*4;
  size_t uniOff = A(((h7B + 255) & ~(size_t)255) + h8B);
  float* h7   = (float*)(ws + uniOff);
  float* h8   = (float*)(ws + uniOff + ((h7B + 255) & ~(size_t)255));
  if (off > ws_size) return;

  dim3 b256(256), b512(512);
  int nb0 = (N + 255) / 256;
  prep0<<<dim3(nb0 + 768 + 384 + 512), b256, 0, stream>>>(
      curr_pos, node_t, x0CN, xh0, xx0, N, W6, w6t, W7, w7xt, W8, w8t);

  dim3 gknn(N/16, 2);
  dim3 gprep(5*(N/256));
  dim3 gec(N/8);
  dim3 gfin((N+255)/256);

  // round 1
  knn_mfma<32><<<gknn, b512, 0, stream>>>(xh0, xx0, pl, N);
  prep_knn_uv<12><<<gprep, b256, 0, stream>>>(pl, idxb, x0CN, W1, bn1, Ut, Vtb, N);
  edge2<true><<<gec, b256, 0, stream>>>(Ut, Vtb, idxb, W2, bn2, x1CN, xh1, xx1, N);
  // round 2
  knn_mfma<64><<<gknn, b512, 0, stream>>>(xh1, xx1, pl, N);
  prep_knn_uv<64><<<gprep, b256, 0, stream>>>(pl, idxb, x1CN, W3, bn3, Ut, Vtb, N);
  edge2<true><<<gec, b256, 0, stream>>>(Ut, Vtb, idxb, W4, bn4, x2CN, xh2, xx2, N);
  // round 3
  knn_mfma<64><<<gknn, b512, 0, stream>>>(xh2, xx2, pl, N);
  prep_knn_uv<64><<<gprep, b256, 0, stream>>>(pl, idxb, x2CN, W5, bn5, Ut, Vtb, N);
  edge2<false><<<gec, b256, 0, stream>>>(Ut, Vtb, idxb, nullptr, nullptr, x3CN, nullptr, nullptr, N);
  // head
  conv_fused<true><<<dim3(N/128, 16), b256, 0, stream>>>(w6t, 1024, x1CN, 64, x2CN, 64, x3CN, 64, bn6, nullptr, gpart, N);
  gmax_final<<<dim3(4), b256, 0, stream>>>(gpart, gbuf, 1024, N/128);
  bias7_kernel<<<dim3(128), b256, 0, stream>>>(W7, gbuf, b7);
  conv_fused<false><<<dim3(N/128, 8), b256, 0, stream>>>(w7xt, 512, x1CN, 64, x2CN, 64, x3CN, 64, bn7, b7, h7, N);
  conv_fused<false><<<dim3(N/128, 4), b256, 0, stream>>>(w8t, 256, h7, 512, nullptr, 0, nullptr, 0, bn8, nullptr, h8, N);
  w9_kernel<<<gfin, b256, 0, stream>>>(W9, h8, out, N);
}

// Round 14
// 819.170 us; speedup vs baseline: 1.2503x; 1.0349x over previous
//
#include <hip/hip_runtime.h>
#include <hip/hip_bf16.h>

#define KNN_K 20
typedef _Float16 f16;
typedef _Float16 half8 __attribute__((ext_vector_type(8)));
typedef float f32x4 __attribute__((ext_vector_type(4)));

__device__ __forceinline__ float lrelu(float x){ return x >= 0.f ? x : 0.2f*x; }
__device__ __forceinline__ f16 us2h(unsigned short u){ union{unsigned short u; f16 h;} x; x.u=u; return x.h; }
__device__ __forceinline__ unsigned short h2us(f16 h){ union{unsigned short u; f16 h;} x; x.h=h; return x.u; }

// u32 key: [31:16] order-mapped f16 distance (desc), [15:0] ~m (idx asc). Unique, always > 0.
__device__ __forceinline__ unsigned pack_key16(f16 v, int m){
  unsigned u = h2us(v);
  unsigned s = (u & 0x8000u) ? ((~u) & 0xFFFFu) : (u | 0x8000u);
  return (s << 16) | ((~(unsigned)m) & 0xFFFFu);
}

// UNGUARDED sorted-desc insert: min/max carry chain (key below tk[19] falls off the end).
__device__ __forceinline__ void insert_nc(unsigned* tk, unsigned key){
  unsigned c = key;
  #pragma unroll
  for (int j=0;j<KNN_K;++j){
    unsigned hi = max(tk[j], c);
    unsigned lo = min(tk[j], c);
    tk[j] = hi;
    c = lo;
  }
}

__device__ __forceinline__ void merge_sorted(unsigned* tk, const unsigned* src){
  #pragma unroll
  for (int j=0;j<KNN_K;++j){
    unsigned key = src[j];
    if (key <= tk[KNN_K-1]) break;
    insert_nc(tk, key);
  }
}

// ---------------- prep0: build x0 + all weight transposes (fused) ----------------
__global__ __launch_bounds__(256) void prep0(
    const float* __restrict__ pos, const int* __restrict__ nt,
    float* __restrict__ x0CN, unsigned short* __restrict__ xh0,
    unsigned short* __restrict__ xx0, int N,
    const float* __restrict__ W6, float* __restrict__ w6t,
    const float* __restrict__ W7, float* __restrict__ w7xt,
    const float* __restrict__ W8, float* __restrict__ w8t)
{
  int b = blockIdx.x, tid = threadIdx.x;
  int nb0 = (N + 255) >> 8;
  if (b < nb0){
    int n = b*256 + tid;
    if (n >= N) return;
    float v[12];
    v[0]=pos[n*3+0]; v[1]=pos[n*3+1]; v[2]=pos[n*3+2];
    int t = nt[n];
    #pragma unroll
    for (int c=0;c<9;++c) v[3+c] = (t==c) ? 1.f : 0.f;
    float xa = 0.f;
    #pragma unroll
    for (int c=0;c<12;++c){
      x0CN[(size_t)c*N+n] = v[c];
      f16 h = (f16)v[c];
      float hf = (float)h;
      xh0[(size_t)n*32+c] = h2us(h);
      f16 pe = (f16)(hf*hf);       // elementwise xh*xh rounds to f16
      xa += (float)pe;             // f32 accumulation (jax upcast semantics)
    }
    #pragma unroll
    for (int c=12;c<32;++c) xh0[(size_t)n*32+c] = 0;
    xx0[n] = h2us((f16)xa);
    return;
  }
  b -= nb0;
  if (b < 768){                      // W6: [1024][192] -> w6t[c*1024+o]
    int i = b*256 + tid;
    int o = i / 192, c = i % 192;
    w6t[(size_t)c*1024 + o] = W6[(size_t)o*192 + c];
    return;
  }
  b -= 768;
  if (b < 384){                      // W7 x-part: [512][1216], coff 1024, C=192
    int i = b*256 + tid;
    int o = i / 192, c = i % 192;
    w7xt[(size_t)c*512 + o] = W7[(size_t)o*1216 + 1024 + c];
    return;
  }
  b -= 384;
  {                                  // W8: [256][512]
    int i = b*256 + tid;
    int o = i / 512, c = i % 512;
    w8t[(size_t)c*256 + o] = W8[(size_t)o*512 + c];
  }
}

// ---------------- fused MFMA kNN v5: single pass over ALL m, writes idx directly ----------------
// grid N/16 = 512 blocks (2/CU, uniformly resident), 512 thr. LDS 57344 B.
template<int C>
__global__ __launch_bounds__(512) void knn_mfma(
    const unsigned short* __restrict__ xh,  // [N][C] f16 bits
    const unsigned short* __restrict__ xx,  // [N]   f16 bits
    int* __restrict__ idx, int N)
{
  __shared__ unsigned lists[32][16][KNN_K];   // 40960 B
  __shared__ unsigned short xxs[8192];        // 16384 B: all xx
  int tid = threadIdx.x;
  int w = tid >> 6, lane = tid & 63;
  int g = lane >> 4, c = lane & 15;
  int n0 = blockIdx.x * 16;
  int ntiles = N >> 6;

  ((uint4*)xxs)[tid]       = ((const uint4*)xx)[tid];
  ((uint4*)xxs)[tid + 512] = ((const uint4*)xx)[tid + 512];

  half8 bfrag[C/32];
  #pragma unroll
  for (int kc=0; kc<C/32; ++kc)
    bfrag[kc] = *reinterpret_cast<const half8*>(xh + (size_t)(n0 + c)*C + kc*32 + g*8);
  f16 qxx = us2h(xx[n0 + c]);
  __syncthreads();

  unsigned tk[KNN_K];
  #pragma unroll
  for (int j=0;j<KNN_K;++j) tk[j] = 0u;

  const unsigned short* ap = xh + (size_t)(w*64 + c)*C + g*8;
  int ml = w*64 + g*4;

  for (int t = w; t < ntiles; t += 8){
    #pragma unroll
    for (int msub=0; msub<4; ++msub){
      const unsigned short* ap2 = ap + msub*(16*C);
      f32x4 acc = {0.f,0.f,0.f,0.f};
      #pragma unroll
      for (int kc=0; kc<C/32; ++kc){
        half8 af = *reinterpret_cast<const half8*>(ap2 + kc*32);
        acc = __builtin_amdgcn_mfma_f32_16x16x32_f16(af, bfrag[kc], acc, 0, 0, 0);
      }
      #pragma unroll
      for (int j=0;j<4;++j){
        int mloc = ml + msub*16 + j;
        f16 dh = (f16)acc[j];          // einsum output rounds to f16
        f16 mi = dh * (f16)(-2.0f);    // inner = -2*dot
        f16 xm = us2h(xxs[mloc]);
        f16 t1 = (-xm) - mi;           // (-xx[m] - inner)
        f16 pdh = t1 - qxx;            // ... - xx[n]
        insert_nc(tk, pack_key16(pdh, mloc));
      }
    }
    ap += (size_t)512*C;
    ml += 512;
  }

  {
    unsigned* dst = lists[w*4 + g][c];
    #pragma unroll
    for (int j=0;j<KNN_K;++j) dst[j] = tk[j];
  }
  __syncthreads();

  unsigned tk2[KNN_K];
  if (tid < 128){
    int n = tid >> 3, q = tid & 7;
    #pragma unroll
    for (int j=0;j<KNN_K;++j) tk2[j] = lists[q*4][n][j];
    for (int li=1; li<4; ++li) merge_sorted(tk2, lists[q*4 + li][n]);
  }
  __syncthreads();
  if (tid < 128){
    int n = tid >> 3, q = tid & 7;
    unsigned* dst = lists[q][n];
    #pragma unroll
    for (int j=0;j<KNN_K;++j) dst[j] = tk2[j];
  }
  __syncthreads();
  if (tid < 32){
    int n = tid >> 1, h = tid & 1;
    #pragma unroll
    for (int j=0;j<KNN_K;++j) tk2[j] = lists[h*4][n][j];
    for (int li=1; li<4; ++li) merge_sorted(tk2, lists[h*4 + li][n]);
  }
  __syncthreads();
  if (tid < 32){
    int n = tid >> 1, h = tid & 1;
    unsigned* dst = lists[h][n];
    #pragma unroll
    for (int j=0;j<KNN_K;++j) dst[j] = tk2[j];
  }
  __syncthreads();
  if (tid < 16){
    int n = tid;
    #pragma unroll
    for (int j=0;j<KNN_K;++j) tk2[j] = lists[0][n][j];
    merge_sorted(tk2, lists[1][n]);
    #pragma unroll
    for (int j=0;j<KNN_K;++j)
      idx[(size_t)(n0 + n)*KNN_K + j] = (int)((~tk2[j]) & 0xFFFFu);
  }
}

// ---------------- per-point U/V precompute: Ut = t*(Wd X); Vtb = t*((Wc-Wd)X - m) + b ----------------
template<int CIN>
__global__ __launch_bounds__(256) void uv_kernel(
    const float* __restrict__ xCN, const float* __restrict__ W,  // [64][2*CIN]
    const float* __restrict__ bn,
    float* __restrict__ Ut, float* __restrict__ Vtb, int N)
{
  __shared__ float Ws[32][CIN];
  int tid = threadIdx.x;
  int mode = blockIdx.y;      // 0 = U (neighbor term), 1 = V (center term)
  int ob = blockIdx.z * 32;
  for (int i = tid; i < 32*CIN; i += 256){
    int oo = i / CIN, cc = i % CIN;
    float wd = W[(size_t)(ob+oo)*(2*CIN) + cc];
    float wc = W[(size_t)(ob+oo)*(2*CIN) + CIN + cc];
    Ws[oo][cc] = mode ? (wc - wd) : wd;
  }
  __syncthreads();
  int n = blockIdx.x*256 + tid;
  float x[CIN];
  #pragma unroll
  for (int c2=0;c2<CIN;++c2) x[c2] = xCN[(size_t)c2*N + n];
  float acc[32];
  #pragma unroll
  for (int oo=0;oo<32;++oo) acc[oo] = 0.f;
  #pragma unroll 4
  for (int c2=0;c2<CIN;++c2){
    float xv = x[c2];
    #pragma unroll
    for (int oo=0;oo<32;++oo) acc[oo] = fmaf(Ws[oo][c2], xv, acc[oo]);
  }
  float* dst = mode ? Vtb : Ut;
  #pragma unroll
  for (int oo=0;oo<32;++oo){
    int o = ob + oo;
    float t = bn[o] / sqrtf(bn[192+o] + 1e-5f);
    float val = mode ? fmaf(acc[oo] - bn[128+o], t, bn[64+o]) : acc[oo]*t;
    dst[(size_t)n*64 + o] = val;
  }
}

// ---------------- edge conv v3: both q's interleaved + (idx, Ut-row) prefetch ----------------
template<bool SECOND>
__global__ __launch_bounds__(256) void edge2(
    const float* __restrict__ Ut, const float* __restrict__ Vtb,
    const int* __restrict__ idx,
    const float* __restrict__ W2, const float* __restrict__ bn2,
    float* __restrict__ outCN, unsigned short* __restrict__ outh,
    unsigned short* __restrict__ outxx, int N)
{
  __shared__ float eb[2][4][64];    // [q][wave][o]
  int w = threadIdx.x >> 6, o = threadIdx.x & 63;
  float w2r[64]; float t2=0.f,b2=0.f,m2=0.f;
  if (SECOND){
    #pragma unroll
    for (int c4=0;c4<16;++c4){
      float4 wv = *reinterpret_cast<const float4*>(W2 + (size_t)o*64 + c4*4);
      w2r[c4*4+0]=wv.x; w2r[c4*4+1]=wv.y; w2r[c4*4+2]=wv.z; w2r[c4*4+3]=wv.w;
    }
    t2 = bn2[o]/sqrtf(bn2[192+o]+1e-5f); b2 = bn2[64+o]; m2 = bn2[128+o];
  }
  int n0q = blockIdx.x*8 + w*2;
  float vo0 = Vtb[(size_t)n0q*64 + o];
  float vo1 = Vtb[(size_t)(n0q+1)*64 + o];
  const int* ip0 = idx + (size_t)n0q*KNN_K;
  const int* ip1 = idx + (size_t)(n0q+1)*KNN_K;
  int j0 = ip0[0], j1 = ip1[0];
  float u0 = Ut[(size_t)j0*64 + o], u1 = Ut[(size_t)j1*64 + o];
  float best0 = -INFINITY, best1 = -INFINITY;
  #pragma unroll 1
  for (int k=0;k<KNN_K;++k){
    float u0c = u0, u1c = u1;
    if (k < KNN_K-1){
      j0 = ip0[k+1]; j1 = ip1[k+1];
      u0 = Ut[(size_t)j0*64 + o];     // prefetch next rows while computing
      u1 = Ut[(size_t)j1*64 + o];
    }
    float e0 = lrelu(u0c + vo0);
    float e1 = lrelu(u1c + vo1);
    if (SECOND){
      eb[0][w][o] = e0;
      eb[1][w][o] = e1;
      const float* ep0 = eb[0][w];
      const float* ep1 = eb[1][w];
      float s00=0.f,s01=0.f,s02=0.f,s03=0.f;
      float s10=0.f,s11=0.f,s12=0.f,s13=0.f;
      #pragma unroll
      for (int c4=0;c4<16;++c4){
        float4 ev0 = *reinterpret_cast<const float4*>(ep0 + c4*4);
        float4 ev1 = *reinterpret_cast<const float4*>(ep1 + c4*4);
        s00 = fmaf(w2r[c4*4+0], ev0.x, s00);
        s01 = fmaf(w2r[c4*4+1], ev0.y, s01);
        s02 = fmaf(w2r[c4*4+2], ev0.z, s02);
        s03 = fmaf(w2r[c4*4+3], ev0.w, s03);
        s10 = fmaf(w2r[c4*4+0], ev1.x, s10);
        s11 = fmaf(w2r[c4*4+1], ev1.y, s11);
        s12 = fmaf(w2r[c4*4+2], ev1.z, s12);
        s13 = fmaf(w2r[c4*4+3], ev1.w, s13);
      }
      float sA = (s00+s01)+(s02+s03);
      float sB = (s10+s11)+(s12+s13);
      best0 = fmaxf(best0, lrelu(fmaf(sA - m2, t2, b2)));
      best1 = fmaxf(best1, lrelu(fmaf(sB - m2, t2, b2)));
    } else {
      best0 = fmaxf(best0, e0);
      best1 = fmaxf(best1, e1);
    }
  }
  outCN[(size_t)o*N + n0q]     = best0;
  outCN[(size_t)o*N + n0q + 1] = best1;
  if (SECOND){
    f16 h0 = (f16)best0; float hf0 = (float)h0;
    f16 h1 = (f16)best1; float hf1 = (float)h1;
    outh[(size_t)n0q*64 + o]     = h2us(h0);
    outh[(size_t)(n0q+1)*64 + o] = h2us(h1);
    float p0 = (float)(f16)(hf0*hf0);
    float p1 = (float)(f16)(hf1*hf1);
    #pragma unroll
    for (int s2s=32;s2s>=1;s2s>>=1){
      p0 += __shfl_xor(p0, s2s, 64);
      p1 += __shfl_xor(p1, s2s, 64);
    }
    if (o == 0){
      outxx[n0q]   = h2us((f16)p0);
      outxx[n0q+1] = h2us((f16)p1);
    }
  }
}

// ---------------- fused 1x1-conv v3: o-tile 64 x n-tile 128, LDS-staged weights ----------------
template<bool DOMAX>
__global__ __launch_bounds__(256) void conv_fused(
    const float* __restrict__ WT, int O,
    const float* __restrict__ sA, int cAn,
    const float* __restrict__ sB, int cBn,
    const float* __restrict__ sC, int cCn,
    const float* __restrict__ bnp,
    const float* __restrict__ extra,
    float* __restrict__ out, int N)
{
  __shared__ float ws[32][68];
  int tid = threadIdx.x;
  int ln = tid & 63;
  int og = (tid >> 6) * 16;          // wave-uniform o sub-offset
  int n0 = blockIdx.x*128;
  int ob = blockIdx.y*64;
  int n = n0 + ln*2;
  float a0[16], a1[16];
  #pragma unroll
  for (int i=0;i<16;++i){ a0[i]=0.f; a1[i]=0.f; }

  const float* srcs[3] = {sA, sB, sC};
  int cnts[3] = {cAn, cBn, cCn};
  int cbase = 0;
  #pragma unroll 1
  for (int sidx=0; sidx<3; ++sidx){
    const float* s = srcs[sidx];
    if (!s) continue;
    int cn = cnts[sidx];
    #pragma unroll 1
    for (int c0=0; c0<cn; c0+=32){
      __syncthreads();
      #pragma unroll
      for (int r=0;r<8;++r){
        int i = r*256 + tid;
        int cc = i >> 6, oo = i & 63;
        ws[cc][oo] = WT[(size_t)(cbase+c0+cc)*O + ob + oo];
      }
      __syncthreads();
      #pragma unroll 4
      for (int cc=0; cc<32; ++cc){
        float2 xv = *reinterpret_cast<const float2*>(s + (size_t)(c0+cc)*N + n);
        const float* wr = &ws[cc][og];
        #pragma unroll
        for (int i=0;i<16;++i){
          a0[i] = fmaf(wr[i], xv.x, a0[i]);
          a1[i] = fmaf(wr[i], xv.y, a1[i]);
        }
      }
    }
    cbase += cn;
  }
  #pragma unroll
  for (int i=0;i<16;++i){
    int oG = ob + og + i;
    float t = bnp[oG] / sqrtf(bnp[3*O+oG] + 1e-5f);
    float e = extra ? extra[oG] : 0.f;
    float mm = bnp[2*O+oG], bb = bnp[1*O+oG];
    a0[i] = lrelu(fmaf((a0[i]+e) - mm, t, bb));
    a1[i] = lrelu(fmaf((a1[i]+e) - mm, t, bb));
  }
  if (!DOMAX){
    #pragma unroll
    for (int i=0;i<16;++i){
      float2 st = {a0[i], a1[i]};
      *reinterpret_cast<float2*>(out + (size_t)(ob+og+i)*N + n) = st;
    }
  } else {
    #pragma unroll
    for (int i=0;i<16;++i){
      float v = fmaxf(a0[i], a1[i]);
      #pragma unroll
      for (int s=32;s>=1;s>>=1) v = fmaxf(v, __shfl_xor(v, s, 64));
      if (ln == 0) out[(size_t)(ob+og+i)*gridDim.x + blockIdx.x] = v;
    }
  }
}

__global__ __launch_bounds__(256) void gmax_final(
    const float* __restrict__ gpart, float* __restrict__ g, int O, int P)
{
  int o = blockIdx.x*256 + threadIdx.x;
  if (o >= O) return;
  float m = -INFINITY;
  for (int p=0;p<P;++p) m = fmaxf(m, gpart[(size_t)o*P + p]);
  g[o] = m;
}

// lane-parallel over c with shuffle reduce; one o per wave
__global__ __launch_bounds__(256) void bias7_kernel(
    const float* __restrict__ W7, const float* __restrict__ g, float* __restrict__ b7)
{
  int w = threadIdx.x >> 6, ln = threadIdx.x & 63;
  int o = blockIdx.x*4 + w;
  if (o >= 512) return;
  float a = 0.f;
  #pragma unroll
  for (int c0=0; c0<1024; c0+=64)
    a = fmaf(W7[(size_t)o*1216 + c0 + ln], g[c0 + ln], a);
  #pragma unroll
  for (int s=32;s>=1;s>>=1) a += __shfl_xor(a, s, 64);
  if (ln == 0) b7[o] = a;
}

__global__ __launch_bounds__(256) void w9_kernel(
    const float* __restrict__ W9, const float* __restrict__ h8, float* __restrict__ out, int N)
{
  int n = blockIdx.x*256 + threadIdx.x;
  if (n >= N) return;
  float a0=0.f, a1=0.f, a2=0.f;
  for (int c=0;c<256;++c){
    float xv = h8[(size_t)c*N + n];
    a0 = fmaf(W9[c],       xv, a0);
    a1 = fmaf(W9[256+c],   xv, a1);
    a2 = fmaf(W9[512+c],   xv, a2);
  }
  out[(size_t)n*3+0]=a0; out[(size_t)n*3+1]=a1; out[(size_t)n*3+2]=a2;
}

extern "C" void kernel_launch(void* const* d_in, const int* in_sizes, int n_in,
                              void* d_out, int out_size, void* d_ws, size_t ws_size,
                              hipStream_t stream) {
  const float* curr_pos = (const float*)d_in[0];
  const int*   node_t   = (const int*)  d_in[1];
  const float* W1 = (const float*)d_in[2];
  const float* W2 = (const float*)d_in[3];
  const float* W3 = (const float*)d_in[4];
  const float* W4 = (const float*)d_in[5];
  const float* W5 = (const float*)d_in[6];
  const float* W6 = (const float*)d_in[7];
  const float* W7 = (const float*)d_in[8];
  const float* W8 = (const float*)d_in[9];
  const float* W9 = (const float*)d_in[10];
  const float* bn1 = (const float*)d_in[11];
  const float* bn2 = (const float*)d_in[12];
  const float* bn3 = (const float*)d_in[13];
  const float* bn4 = (const float*)d_in[14];
  const float* bn5 = (const float*)d_in[15];
  const float* bn6 = (const float*)d_in[16];
  const float* bn7 = (const float*)d_in[17];
  const float* bn8 = (const float*)d_in[18];
  float* out = (float*)d_out;

  const int N = in_sizes[0] / 3;

  char* ws = (char*)d_ws;
  size_t off = 0;
  auto A = [&](size_t b){ size_t o = off; off = (o + b + 255) & ~(size_t)255; return o; };

  float* x0CN = (float*)(ws + A((size_t)N*12*4));
  unsigned short* xh0 = (unsigned short*)(ws + A((size_t)N*32*2));
  unsigned short* xx0 = (unsigned short*)(ws + A((size_t)N*2));
  float* x1CN = (float*)(ws + A((size_t)N*64*4));
  unsigned short* xh1 = (unsigned short*)(ws + A((size_t)N*64*2));
  unsigned short* xx1 = (unsigned short*)(ws + A((size_t)N*2));
  float* x2CN = (float*)(ws + A((size_t)N*64*4));
  unsigned short* xh2 = (unsigned short*)(ws + A((size_t)N*64*2));
  unsigned short* xx2 = (unsigned short*)(ws + A((size_t)N*2));
  float* x3CN = (float*)(ws + A((size_t)N*64*4));
  int* idxb = (int*)(ws + A((size_t)N*KNN_K*4));
  float* Ut  = (float*)(ws + A((size_t)N*64*4));
  float* Vtb = (float*)(ws + A((size_t)N*64*4));
  float* w6t  = (float*)(ws + A((size_t)192*1024*4));
  float* w7xt = (float*)(ws + A((size_t)192*512*4));
  float* w8t  = (float*)(ws + A((size_t)512*256*4));
  float* gpart= (float*)(ws + A((size_t)1024*(N/64)*4));
  float* gbuf = (float*)(ws + A((size_t)1024*4));
  float* b7   = (float*)(ws + A((size_t)512*4));

  size_t h7B   = (size_t)512*N*4;
  size_t h8B   = (size_t)256*N*4;
  size_t uniOff = A(((h7B + 255) & ~(size_t)255) + h8B);
  float* h7   = (float*)(ws + uniOff);
  float* h8   = (float*)(ws + uniOff + ((h7B + 255) & ~(size_t)255));
  if (off > ws_size) return;

  dim3 b256(256), b512(512);
  int nb0 = (N + 255) / 256;
  prep0<<<dim3(nb0 + 768 + 384 + 512), b256, 0, stream>>>(
      curr_pos, node_t, x0CN, xh0, xx0, N, W6, w6t, W7, w7xt, W8, w8t);

  dim3 gknn(N/16);
  dim3 guv(N/256, 2, 2);
  dim3 gec(N/8);
  dim3 gfin((N+255)/256);

  // round 1
  knn_mfma<32><<<gknn, b512, 0, stream>>>(xh0, xx0, idxb, N);
  uv_kernel<12><<<guv, b256, 0, stream>>>(x0CN, W1, bn1, Ut, Vtb, N);
  edge2<true><<<gec, b256, 0, stream>>>(Ut, Vtb, idxb, W2, bn2, x1CN, xh1, xx1, N);
  // round 2
  knn_mfma<64><<<gknn, b512, 0, stream>>>(xh1, xx1, idxb, N);
  uv_kernel<64><<<guv, b256, 0, stream>>>(x1CN, W3, bn3, Ut, Vtb, N);
  edge2<true><<<gec, b256, 0, stream>>>(Ut, Vtb, idxb, W4, bn4, x2CN, xh2, xx2, N);
  // round 3
  knn_mfma<64><<<gknn, b512, 0, stream>>>(xh2, xx2, idxb, N);
  uv_kernel<64><<<guv, b256, 0, stream>>>(x2CN, W5, bn5, Ut, Vtb, N);
  edge2<false><<<gec, b256, 0, stream>>>(Ut, Vtb, idxb, nullptr, nullptr, x3CN, nullptr, nullptr, N);
  // head
  conv_fused<true><<<dim3(N/128, 16), b256, 0, stream>>>(w6t, 1024, x1CN, 64, x2CN, 64, x3CN, 64, bn6, nullptr, gpart, N);
  gmax_final<<<dim3(4), b256, 0, stream>>>(gpart, gbuf, 1024, N/128);
  bias7_kernel<<<dim3(128), b256, 0, stream>>>(W7, gbuf, b7);
  conv_fused<false><<<dim3(N/128, 8), b256, 0, stream>>>(w7xt, 512, x1CN, 64, x2CN, 64, x3CN, 64, bn7, b7, h7, N);
  conv_fused<false><<<dim3(N/128, 4), b256, 0, stream>>>(w8t, 256, h7, 512, nullptr, 0, nullptr, 0, bn8, nullptr, h8, N);
  w9_kernel<<<gfin, b256, 0, stream>>>(W9, h8, out, N);
}